// Round 1
// baseline (145.380 us; speedup 1.0000x reference)
//
#include <hip/hip_runtime.h>

// Problem constants (fixed by setup_inputs): B=32, C=64, H=W=32, N=16 branches.
#define CH      64
#define BATCH   32
#define NBR     16
#define HW      1024          // H*W
#define NPC     32768         // elements per channel = BATCH*HW

// ---------------------------------------------------------------------------
// Kernel A: per-(group, channel) partial sum / sumsq.
// grid = 512 blocks: c = blockIdx & 63, g = blockIdx >> 6 (8 batch groups of 4).
// Each block reads 4096 elements (1024 float4, fully coalesced) and writes one
// deterministic partial slot -> no atomics, no workspace zeroing required.
// ---------------------------------------------------------------------------
__global__ void __launch_bounds__(256) bn_partial(const float* __restrict__ x,
                                                  float* __restrict__ partials) {
    const int c = blockIdx.x & 63;
    const int g = blockIdx.x >> 6;        // 0..7
    const int t = threadIdx.x;            // 0..255

    float s = 0.f, sq = 0.f;
#pragma unroll
    for (int bb = 0; bb < 4; ++bb) {
        const int batch = g * 4 + bb;
        // channel chunk = HW floats = 256 float4; lane t takes float4 #t.
        const float4 v = ((const float4*)x)[(batch * CH + c) * 256 + t];
        s  += v.x + v.y + v.z + v.w;
        sq += v.x * v.x + v.y * v.y + v.z * v.z + v.w * v.w;
    }

    // wave(64)-level shuffle reduction
#pragma unroll
    for (int off = 32; off > 0; off >>= 1) {
        s  += __shfl_down(s, off);
        sq += __shfl_down(sq, off);
    }
    __shared__ float ls[4], lq[4];
    const int wave = t >> 6, lane = t & 63;
    if (lane == 0) { ls[wave] = s; lq[wave] = sq; }
    __syncthreads();
    if (t == 0) {
        const float S = ls[0] + ls[1] + ls[2] + ls[3];
        const float Q = lq[0] + lq[1] + lq[2] + lq[3];
        partials[(g * CH + c) * 2 + 0] = S;
        partials[(g * CH + c) * 2 + 1] = Q;
    }
}

// ---------------------------------------------------------------------------
// Kernel B: finalize. 1 block x 1024 threads, thread t = n*64 + c.
// Folds the 8 partials per channel, then emits per-(n,c) scale/shift so the
// apply kernel is a single FMA per element:
//   out = gamma*(x-mean)*inv + beta = scale*x + shift
// ---------------------------------------------------------------------------
__global__ void __launch_bounds__(1024) bn_finalize(const float* __restrict__ partials,
                                                    const float* __restrict__ gamma,
                                                    const float* __restrict__ beta,
                                                    float* __restrict__ scale,
                                                    float* __restrict__ shift) {
    const int t = threadIdx.x;            // 0..1023
    const int c = t & 63;
    float S = 0.f, Q = 0.f;
#pragma unroll
    for (int g = 0; g < 8; ++g) {
        S += partials[(g * CH + c) * 2 + 0];
        Q += partials[(g * CH + c) * 2 + 1];
    }
    const float mean = S * (1.0f / NPC);
    const float var  = Q * (1.0f / NPC) - mean * mean;
    const float inv  = rsqrtf(var + 1e-5f);
    const float a    = gamma[t] * inv;    // gamma/beta are [N,C] flat; t = n*64+c
    scale[t] = a;
    shift[t] = beta[t] - a * mean;
}

// ---------------------------------------------------------------------------
// Kernel C: broadcast apply. One float4 of x per thread; 16 branch stores.
// x layout [B,C,H,W]: per-(b,c) chunk = 1024 floats = 256 float4, so within a
// 64-lane wave c is uniform -> scale/shift loads are effectively scalar+L1.
// Each of the 16 stores is 64 lanes x 16 B = 1 KB contiguous (coalesced).
// out flat index: ((b*N + n)*C + c)*HW + hw  ==  (b*1024 + n*64 + c)*1024 + hw
// ---------------------------------------------------------------------------
__global__ void __launch_bounds__(256) bn_apply(const float* __restrict__ x,
                                                const float* __restrict__ scale,
                                                const float* __restrict__ shift,
                                                float* __restrict__ out) {
    const int idx = blockIdx.x * 256 + threadIdx.x;   // float4 index, 0..524287
    const int b   = idx >> 14;          // / (C*HW/4 = 16384)
    const int c   = (idx >> 8) & 63;    // / 256 float4 per channel chunk
    const int hw4 = idx & 255;

    const float4 v = ((const float4*)x)[idx];
    float4* o4 = (float4*)out;

#pragma unroll
    for (int n = 0; n < NBR; ++n) {
        const float a = scale[n * CH + c];
        const float s = shift[n * CH + c];
        float4 o;
        o.x = a * v.x + s;
        o.y = a * v.y + s;
        o.z = a * v.z + s;
        o.w = a * v.w + s;
        o4[((b * 1024 + n * CH + c) << 8) + hw4] = o;
    }
}

extern "C" void kernel_launch(void* const* d_in, const int* in_sizes, int n_in,
                              void* d_out, int out_size, void* d_ws, size_t ws_size,
                              hipStream_t stream) {
    const float* x     = (const float*)d_in[0];   // [32,64,32,32]
    const float* gamma = (const float*)d_in[1];   // [16,64]
    const float* beta  = (const float*)d_in[2];   // [16,64]
    float* out = (float*)d_out;                   // [32,1024,32,32]
    float* ws  = (float*)d_ws;

    float* partials = ws;          // 1024 floats (8 groups x 64 ch x {S,Q})
    float* scale    = ws + 1024;   // 1024 floats
    float* shift    = ws + 2048;   // 1024 floats

    bn_partial <<<512, 256, 0, stream>>>(x, partials);
    bn_finalize<<<1, 1024, 0, stream>>>(partials, gamma, beta, scale, shift);
    bn_apply   <<<2048, 256, 0, stream>>>(x, scale, shift, out);
}